// Round 10
// baseline (77.971 us; speedup 1.0000x reference)
//
#include <hip/hip_runtime.h>

// Problem constants (AdaptivePruner)
#define NB   256   // batch
#define NTOK 197   // tokens incl cls
#define NP   196   // patch tokens
#define ND   768   // channels
#define LEN1 101   // one-level DWT length
#define LEN2 54    // two-level DWT length
#define OUTROWS 102
#define NGRP 51               // row-pairs per batch
#define NPAIR (NB * NGRP)     // 13056 total pairs
#define NBLK 2048             // persistent blocks (8 per CU), %8==0

typedef float f4 __attribute__((ext_vector_type(4)));

// ---------------- Gini kernel: one block per batch row ----------------
// gini = 2*sum(rank_i*p_i)/(N*sum(p)+1e-8) - (N+1)/N, rank ascending 1-based.
// Rank by counting (tie-order irrelevant to the sum); double accumulation.
__global__ __launch_bounds__(256)
void gini_kernel(const float* __restrict__ attn, int* __restrict__ flags) {
    __shared__ float  row[NP];
    __shared__ double sS[256];
    __shared__ double sT[256];
    const int b   = blockIdx.x;
    const int tid = threadIdx.x;
    if (tid < NP) row[tid] = attn[b * NP + tid];
    __syncthreads();
    double sj = 0.0, tj = 0.0;
    if (tid < NP) {
        const float p = row[tid];
        int rank = 1;
        for (int k = 0; k < NP; ++k) {
            const float q = row[k];
            rank += (q < p) || (q == p && k < tid);
        }
        sj = (double)rank * (double)p;
        tj = (double)p;
    }
    sS[tid] = sj; sT[tid] = tj;
    __syncthreads();
    for (int off = 128; off > 0; off >>= 1) {
        if (tid < off) { sS[tid] += sS[tid + off]; sT[tid] += sT[tid + off]; }
        __syncthreads();
    }
    if (tid == 0) {
        const double S = sS[0], T = sT[0];
        const double gini = 2.0 * S / ((double)NP * T + 1e-8)
                          - (double)(NP + 1) / (double)NP;
        flags[b] = (gini > (double)0.333f) ? 1 : 0;
    }
}

// ---------------- Main DWT kernel (persistent blocks) ----------------
// 2048 persistent blocks (192 threads each). Block c owns a CONTIGUOUS
// chunk of 6-7 row-pairs (balanced split of 13056), so consecutive pairs
// (mostly same batch, same flag) run back-to-back with cross-iteration
// load/compute overlap. Chunk->XCD swizzle keeps neighboring chunks on
// the same XCD's L2. Per-pair body = best measured (round-3/7) version.
__global__ __launch_bounds__(192)
void dwt_kernel(const float* __restrict__ x, const int* __restrict__ flags,
                float* __restrict__ out_x, float* __restrict__ out_mask) {
    const float h[8] = {0.23037781330885523f,  0.7148465705525415f,
                        0.6308807679295904f,  -0.02798376941698385f,
                       -0.18703481171888114f,  0.030841381835986965f,
                        0.032883011666982945f,-0.010597401784997278f};
    // composite two-level filter g2[m] = sum_{2j+l=m} h[j]*h[l] (constant-folded)
    float g2[22];
    #pragma unroll
    for (int m = 0; m < 22; ++m) {
        float s = 0.f;
        #pragma unroll
        for (int j = 0; j < 8; ++j) {
            const int l = m - 2 * j;
            if (0 <= l && l < 8) s += h[j] * h[l];
        }
        g2[m] = s;
    }

    // chunk id with XCD swizzle: XCD j gets chunks [j*256, (j+1)*256)
    const int hw = blockIdx.x;
    const int ck = (hw & 7) * (NBLK / 8) + (hw >> 3);
    // balanced contiguous split of NPAIR pairs over NBLK chunks
    const int q = NPAIR / NBLK;              // 6
    const int r = NPAIR % NBLK;              // 768
    const int start = ck * q + (ck < r ? ck : r);
    const int len   = q + (ck < r ? 1 : 0);

    const int c  = threadIdx.x;              // channel float4 group
    const int d0 = c * 4;

    for (int it = 0; it < len; ++it) {
        const int pid = start + it;
        const int b   = pid / NGRP;
        const int grp = pid - b * NGRP;      // 0..50

        const float* __restrict__ px = x + ((size_t)b * NTOK + 1) * ND + d0;
        float* __restrict__ po = out_x + (size_t)b * OUTROWS * ND + d0;
        const int flag = flags[b];

        auto raw = [&](int i) -> f4 { return *(const f4*)(px + (size_t)i * ND); };
        auto clamped = [&](int i) -> f4 {
            return (i >= 0 && i < NP) ? *(const f4*)(px + (size_t)i * ND)
                                      : (f4){0.f, 0.f, 0.f, 0.f};
        };

        if (grp == 0) {
            // row 0: cls passthrough (+ mask), row 1: first output row
            const f4 cls = *(const f4*)(x + (size_t)b * NTOK * ND + d0);
            __builtin_nontemporal_store(cls, (f4*)po);
            if (c < OUTROWS) {
                const int outlen = flag ? LEN2 : LEN1;
                out_mask[b * OUTROWS + c] = (c == 0 || (c - 1) < outlen) ? 1.0f : 0.0f;
            }
            f4 y = {0.f, 0.f, 0.f, 0.f};
            if (!flag) {
                y += h[6] * clamped(0);
                y += h[7] * clamped(1);
            } else {
                #pragma unroll
                for (int m = 18; m < 22; ++m) y += g2[m] * clamped(m - 18);
            }
            __builtin_nontemporal_store(y, (f4*)(po + (size_t)ND));
            continue;
        }

        if (!flag) {
            // rows 2g, 2g+1 ; window i in [4g-8, 4g+1]
            const int lo = 4 * grp - 8;
            f4 w[10];
            if (grp >= 2 && grp <= 48) {
                #pragma unroll
                for (int k = 0; k < 10; ++k) w[k] = raw(lo + k);
            } else {
                #pragma unroll
                for (int k = 0; k < 10; ++k) w[k] = clamped(lo + k);
            }
            f4 y0 = {0.f,0.f,0.f,0.f}, y1 = {0.f,0.f,0.f,0.f};
            #pragma unroll
            for (int l = 0; l < 8; ++l) {
                y0 += h[l] * w[l];
                y1 += h[l] * w[l + 2];
            }
            __builtin_nontemporal_store(y0, (f4*)(po + (size_t)(2 * grp) * ND));
            __builtin_nontemporal_store(y1, (f4*)(po + (size_t)(2 * grp + 1) * ND));
        } else {
            const int s0 = 2 * grp - 1;      // rows 2g, 2g+1
            if (s0 < LEN2) {
                // window i in [8g-22, 8g+3], 26 rows, two 13-row halves.
                const int lo = 8 * grp - 22;
                f4 y0 = {0.f,0.f,0.f,0.f}, y1 = {0.f,0.f,0.f,0.f};
                auto run = [&](auto ld) {
                    {   // half A: k = 0..12
                        f4 w[13];
                        #pragma unroll
                        for (int j = 0; j < 13; ++j) w[j] = ld(lo + j);
                        #pragma unroll
                        for (int j = 0; j < 13; ++j) {
                            y0 += g2[j] * w[j];
                            if (j >= 4) y1 += g2[j - 4] * w[j];
                        }
                    }
                    {   // half B: k = 13..25
                        f4 w[13];
                        #pragma unroll
                        for (int j = 0; j < 13; ++j) w[j] = ld(lo + 13 + j);
                        #pragma unroll
                        for (int j = 0; j < 13; ++j) {
                            if (13 + j < 22) y0 += g2[13 + j] * w[j];
                            y1 += g2[9 + j] * w[j];
                        }
                    }
                };
                if (grp >= 3 && grp <= 24) run(raw); else run(clamped);
                if (s0 + 1 >= LEN2) y1 = (f4){0.f,0.f,0.f,0.f};  // row 55 pad
                __builtin_nontemporal_store(y0, (f4*)(po + (size_t)(2 * grp) * ND));
                __builtin_nontemporal_store(y1, (f4*)(po + (size_t)(2 * grp + 1) * ND));
            } else {
                const f4 zero = {0.f,0.f,0.f,0.f};
                __builtin_nontemporal_store(zero, (f4*)(po + (size_t)(2 * grp) * ND));
                __builtin_nontemporal_store(zero, (f4*)(po + (size_t)(2 * grp + 1) * ND));
            }
        }
    }
}

extern "C" void kernel_launch(void* const* d_in, const int* in_sizes, int n_in,
                              void* d_out, int out_size, void* d_ws, size_t ws_size,
                              hipStream_t stream) {
    const float* x    = (const float*)d_in[0];  // (256,197,768) f32
    const float* attn = (const float*)d_in[1];  // (256,196) f32
    float* out_x    = (float*)d_out;                             // (256,102,768)
    float* out_mask = (float*)d_out + (size_t)NB * OUTROWS * ND; // (256,102)
    int* flags = (int*)d_ws;                                     // 256 ints

    gini_kernel<<<NB, 256, 0, stream>>>(attn, flags);
    dwt_kernel<<<NBLK, 192, 0, stream>>>(x, flags, out_x, out_mask);
}